// Round 4
// baseline (338.468 us; speedup 1.0000x reference)
//
#include <hip/hip_runtime.h>

#define N 8192
#define D 128
#define NCLS 16
#define SLOT 512           // bytes per row-slot in the in-place buffer
#define RSTRIDE 256        // u16 stride between consecutive xn rows

typedef unsigned short u16;
typedef __attribute__((ext_vector_type(8))) short v8s;     // 8 bf16 = 4 VGPR
typedef __attribute__((ext_vector_type(16))) float f32x16; // MFMA 32x32 accumulator

// round-to-nearest-even f32 -> bf16
static __device__ inline u16 f2bf(float f) {
  unsigned int u = __builtin_bit_cast(unsigned int, f);
  unsigned int r = u + 0x7fffu + ((u >> 16) & 1u);
  return (u16)(r >> 16);
}

// ---------------- Kernel 1: in-place row-normalize + bf16, scale folded ----------------
// One wave per row; writes xn * sqrt(log2e / t) so that the MFMA product directly
// yields sim * log2e / t  (exp2 of it == exp(sim/t)). Symmetric fold is exact for A==B.
__global__ __launch_bounds__(256) void k_norm(float* __restrict__ buf,
                                              const float* __restrict__ temp) {
  int wave = threadIdx.x >> 6;
  int lane = threadIdx.x & 63;
  int row = blockIdx.x * 4 + wave;
  const float* p = buf + (size_t)row * D + lane * 2;
  float x = p[0], y = p[1];
  float ss = x * x + y * y;
#pragma unroll
  for (int m = 32; m >= 1; m >>= 1) ss += __shfl_xor(ss, m);
  float t = fminf(fmaxf(temp[0], 0.1f), 1.0f);       // ref clamp
  float sc = sqrtf(1.4426950408889634f / t);          // sqrt(log2e / t)
  float inv = sc / fmaxf(sqrtf(ss), 1e-8f);           // ref: max(norm, EPS)
  unsigned int u0 = (unsigned int)f2bf(x * inv);
  unsigned int u1 = (unsigned int)f2bf(y * inv);
  reinterpret_cast<unsigned int*>(buf)[(size_t)row * 128 + lane] = u0 | (u1 << 16);
}

// ---------------- Kernel 2: fused sim GEMM + exp2 + masked row sums ----------------
// grid 512 = 64 row-strips (128 rows) x 8 col-eighths (1024 cols).
// 8 waves/block (512 thr): wave w -> rows rwb+(w>>1)*32, col offset (w&1)*32 within
// each 64-col step, 16 steps. A-frags + pos/tot accumulators in registers all kernel.
// 16 waves/CU (4/SIMD) at VGPR<=128.
__global__ __launch_bounds__(512, 4) void k_sim(float* __restrict__ buf,
                                                const int* __restrict__ tgt) {
  const int tid = threadIdx.x;
  const int wave = tid >> 6;
  const int lane = tid & 63;
  const int l31 = lane & 31;
  const int h = lane >> 5;

  const u16* xnb = reinterpret_cast<const u16*>(buf);

  const int bid = blockIdx.x;
  const int rowstrip = bid >> 3;  // 0..63
  const int cq = bid & 7;         // 0..7
  const int rwb = rowstrip * 128 + (wave >> 1) * 32;  // wave's 32-row base
  const int cbase = cq * 1024 + (wave & 1) * 32;      // wave's col base

  // A fragments: row = rwb + (lane&31), k = kk*16 + 8*h + i
  v8s afrag[8];
  {
    const u16* ap = xnb + (size_t)(rwb + l31) * RSTRIDE + h * 8;
#pragma unroll
    for (int kk = 0; kk < 8; ++kk)
      afrag[kk] = *reinterpret_cast<const v8s*>(ap + kk * 16);
  }

  // class id for each of this lane's 16 accumulator rows
  int trow[16];
#pragma unroll
  for (int r = 0; r < 16; ++r)
    trow[r] = tgt[rwb + ((r & 3) + 8 * (r >> 2) + 4 * h)];

  float tot_acc[16], pos_acc[16];
#pragma unroll
  for (int r = 0; r < 16; ++r) { tot_acc[r] = 0.f; pos_acc[r] = 0.f; }

  const u16* bp = xnb + (size_t)(cbase + l31) * RSTRIDE + h * 8;

  v8s bA[8], bB[8];
#pragma unroll
  for (int kk = 0; kk < 8; ++kk) bA[kk] = *reinterpret_cast<const v8s*>(bp + kk * 16);
#pragma unroll
  for (int kk = 0; kk < 8; ++kk) bB[kk] = *reinterpret_cast<const v8s*>(bp + (size_t)64 * RSTRIDE + kk * 16);

  auto tileCompute = [&](const v8s (&bf)[8], int c0) {
    f32x16 acc;
#pragma unroll
    for (int r = 0; r < 16; ++r) acc[r] = 0.f;
#pragma unroll
    for (int kk = 0; kk < 8; ++kk)
      acc = __builtin_amdgcn_mfma_f32_32x32x16_bf16(afrag[kk], bf[kk], acc, 0, 0, 0);
    int tcol = tgt[c0 + l31];
    if (c0 != rwb) {  // wave-uniform: no diagonal element in this tile
#pragma unroll
      for (int r = 0; r < 16; ++r) {
        float e = exp2f(acc[r]);      // scale pre-folded into operands
        tot_acc[r] += e;
        pos_acc[r] += (tcol == trow[r]) ? e : 0.f;
      }
    } else {          // diagonal tile: zero out row==col element
#pragma unroll
      for (int r = 0; r < 16; ++r) {
        float e = exp2f(acc[r]);
        if (l31 == ((r & 3) + 8 * (r >> 2) + 4 * h)) e = 0.f;
        tot_acc[r] += e;
        pos_acc[r] += (tcol == trow[r]) ? e : 0.f;
      }
    }
  };

  for (int tt = 0; tt < 16; tt += 2) {
    tileCompute(bA, cbase + tt * 64);
    if (tt + 2 < 16) {
      const u16* q = bp + (size_t)(tt + 2) * 64 * RSTRIDE;
#pragma unroll
      for (int kk = 0; kk < 8; ++kk) bA[kk] = *reinterpret_cast<const v8s*>(q + kk * 16);
    }
    tileCompute(bB, cbase + (tt + 1) * 64);
    if (tt + 3 < 16) {
      const u16* q = bp + (size_t)(tt + 3) * 64 * RSTRIDE;
#pragma unroll
      for (int kk = 0; kk < 8; ++kk) bB[kk] = *reinterpret_cast<const v8s*>(q + kk * 16);
    }
  }

  // reduce over 32 cols (lanes of each half) then across wave pairs via LDS
  __shared__ float red_pos[8][32];
  __shared__ float red_tot[8][32];
#pragma unroll
  for (int r = 0; r < 16; ++r) {
    float p = pos_acc[r], q = tot_acc[r];
#pragma unroll
    for (int m = 1; m <= 16; m <<= 1) {
      p += __shfl_xor(p, m);
      q += __shfl_xor(q, m);
    }
    if (l31 == 0) {
      int rl = (r & 3) + 8 * (r >> 2) + 4 * h;
      red_pos[wave][rl] = p;
      red_tot[wave][rl] = q;
    }
  }
  __syncthreads();
  if (tid < 128) {
    int g = tid >> 5, rl = tid & 31;              // row-group 0..3
    int row = rowstrip * 128 + g * 32 + rl;
    float p = red_pos[2 * g][rl] + red_pos[2 * g + 1][rl];
    float q = red_tot[2 * g][rl] + red_tot[2 * g + 1][rl];
    // partials in the free half of row's slot: pos[cq] @ +256B, tot[cq] @ +288B
    float* slot = reinterpret_cast<float*>(reinterpret_cast<char*>(buf) + (size_t)row * SLOT + 256);
    slot[cq] = p;
    slot[8 + cq] = q;
  }
}

// ---------------- Kernel 3: per-row loss + class aggregation -> scalar ----------------
// Single block, 1024 threads, 8 rows each.
__global__ __launch_bounds__(1024) void k_tail(const float* __restrict__ buf,
                                               const int* __restrict__ tgt,
                                               float* __restrict__ out) {
  __shared__ float cs[NCLS], cc[NCLS];
  int tid = threadIdx.x;
  if (tid < NCLS) { cs[tid] = 0.f; cc[tid] = 0.f; }
  __syncthreads();
#pragma unroll
  for (int j = 0; j < 8; ++j) {
    int row = j * 1024 + tid;
    const float4* s4 = reinterpret_cast<const float4*>(
        reinterpret_cast<const char*>(buf) + (size_t)row * SLOT + 256);
    float4 a = s4[0], b = s4[1], c4 = s4[2], d4 = s4[3];
    float pos = a.x + a.y + a.z + a.w + b.x + b.y + b.z + b.w;
    float tot = c4.x + c4.y + c4.z + c4.w + d4.x + d4.y + d4.z + d4.w;
    float loss = logf(tot) - logf(pos);   // -log(pos/tot)
    int c = tgt[row];
    atomicAdd(&cs[c], loss);
    atomicAdd(&cc[c], 1.0f);
  }
  __syncthreads();
  if (tid < 64) {
    int c = tid;  // lanes >= 16 contribute zeros
    float s = 0.f, n = 0.f;
    if (c < NCLS) { s = cs[c]; n = cc[c]; }
    float safe = fmaxf(n, 1.0f);
    float mean = s / safe;
    float inv = (n > 0.5f) ? 1.0f / safe : 0.f;     // counts>0
    float valid = (n > 1.5f) ? 1.f : 0.f;           // counts>1
    float w = (n > 1.5f) ? mean * inv : 0.f;        // select avoids 0*inf -> NaN
    float sinv = inv, sw = w, sv = valid;
#pragma unroll
    for (int m = 1; m <= 32; m <<= 1) {
      sinv += __shfl_xor(sinv, m);
      sw += __shfl_xor(sw, m);
      sv += __shfl_xor(sv, m);
    }
    if (c == 0) out[0] = sw / sinv / sv;  // sum(mean*inv)/sum(inv)/n_valid
  }
}

extern "C" void kernel_launch(void* const* d_in, const int* in_sizes, int n_in,
                              void* d_out, int out_size, void* d_ws, size_t ws_size,
                              hipStream_t stream) {
  float* buf = (float*)d_in[0];        // used as in-place scratch; harness restores
  const int* tgt = (const int*)d_in[1];
  const float* temp = (const float*)d_in[2];
  float* out = (float*)d_out;
  (void)d_ws; (void)ws_size;           // no workspace use

  k_norm<<<N / 4, 256, 0, stream>>>(buf, temp);
  k_sim<<<512, 512, 0, stream>>>(buf, tgt);
  k_tail<<<1, 1024, 0, stream>>>(buf, tgt, out);
}

// Round 5
// 131.342 us; speedup vs baseline: 2.5770x; 2.5770x over previous
//
#include <hip/hip_runtime.h>

#define N 8192
#define D 128
#define NCLS 16
#define SLOT 512           // bytes per row-slot in the in-place buffer
#define RSTRIDE 256        // u16 stride between consecutive xn rows

typedef unsigned short u16;
typedef __attribute__((ext_vector_type(8))) short v8s;     // 8 bf16 = 4 VGPR
typedef __attribute__((ext_vector_type(16))) float f32x16; // MFMA 32x32 accumulator

// round-to-nearest-even f32 -> bf16
static __device__ inline u16 f2bf(float f) {
  unsigned int u = __builtin_bit_cast(unsigned int, f);
  unsigned int r = u + 0x7fffu + ((u >> 16) & 1u);
  return (u16)(r >> 16);
}

// ---------------- Kernel 1: in-place row-normalize + bf16, scale folded ----------------
// Writes xn * sqrt(log2e/t): MFMA product directly yields sim*log2e/t (exp2 == exp(sim/t)).
__global__ __launch_bounds__(256) void k_norm(float* __restrict__ buf,
                                              const float* __restrict__ temp) {
  int wave = threadIdx.x >> 6;
  int lane = threadIdx.x & 63;
  int row = blockIdx.x * 4 + wave;
  const float* p = buf + (size_t)row * D + lane * 2;
  float x = p[0], y = p[1];
  float ss = x * x + y * y;
#pragma unroll
  for (int m = 32; m >= 1; m >>= 1) ss += __shfl_xor(ss, m);
  float t = fminf(fmaxf(temp[0], 0.1f), 1.0f);       // ref clamp
  float sc = sqrtf(1.4426950408889634f / t);          // sqrt(log2e / t)
  float inv = sc / fmaxf(sqrtf(ss), 1e-8f);           // ref: max(norm, EPS)
  unsigned int u0 = (unsigned int)f2bf(x * inv);
  unsigned int u1 = (unsigned int)f2bf(y * inv);
  reinterpret_cast<unsigned int*>(buf)[(size_t)row * 128 + lane] = u0 | (u1 << 16);
}

// ---------------- Kernel 2: fused sim GEMM + exp2 + masked row sums ----------------
// grid 1024 = 128 row-strips (64 rows) x 8 col-eighths (1024 cols).
// 4 waves (256 thr); per 64-col group: stage B rows into LDS (2-phase double buffer,
// swizzled), each wave one 32x32 tile (8 ds_read + 8 MFMA + epilogue).
// Swizzle: LDS[row][ (slot ^ (row&15)) *16B ] = G[row][slot*16B]; linear gload_lds dest
// + inverse-swizzled per-lane global source + swizzled ds_read (rule: both sides).
__global__ __launch_bounds__(256, 3) void k_sim(float* __restrict__ buf,
                                                const int* __restrict__ tgt) {
  __shared__ __align__(16) char lds[2][64 * 256];   // 2 x 16 KB B-tile buffers
  __shared__ float red_pos[4][32];
  __shared__ float red_tot[4][32];

  const int tid = threadIdx.x;
  const int wave = tid >> 6;
  const int lane = tid & 63;
  const int l31 = lane & 31;
  const int h = lane >> 5;

  const u16* xnb = reinterpret_cast<const u16*>(buf);

  const int rowstrip = blockIdx.x >> 3;   // 0..127
  const int cq = blockIdx.x & 7;          // 0..7
  const int rwb = rowstrip * 64 + (wave >> 1) * 32;  // wave's 32-row base
  const int colblock = cq * 1024;
  const int ch = wave & 1;                // wave's 32-col half within a 64-col group

  // A fragments: row = rwb + (lane&31), k = kk*16 + 8*h + j  (held whole kernel)
  v8s afrag[8];
  {
    const u16* ap = xnb + (size_t)(rwb + l31) * RSTRIDE + h * 8;
#pragma unroll
    for (int kk = 0; kk < 8; ++kk)
      afrag[kk] = *reinterpret_cast<const v8s*>(ap + kk * 16);
  }

  // class id for each of this lane's 16 accumulator rows
  int trow[16];
#pragma unroll
  for (int r = 0; r < 16; ++r)
    trow[r] = tgt[rwb + ((r & 3) + 8 * (r >> 2) + 4 * h)];

  float tot_acc[16], pos_acc[16];
#pragma unroll
  for (int r = 0; r < 16; ++r) { tot_acc[r] = 0.f; pos_acc[r] = 0.f; }

  // stage 64 rows x 256B of group g into lds[bsel]; 4 x 16B per thread.
  // linear LDS dest index L = i*256+tid -> (row=L>>4, s=L&15); source slot = s ^ (row&15).
  auto stage = [&](int g, int bsel) {
    int rowbase = colblock + g * 64;
#pragma unroll
    for (int i = 0; i < 4; ++i) {
      int L = i * 256 + tid;
      int row = L >> 4;
      int s = (L & 15) ^ (row & 15);
      const char* src = reinterpret_cast<const char*>(buf) +
                        (size_t)(rowbase + row) * SLOT + s * 16;
      char* dst = &lds[bsel][(i * 256 + wave * 64) * 16];  // wave-uniform base
      __builtin_amdgcn_global_load_lds(
          (const __attribute__((address_space(1))) void*)src,
          (__attribute__((address_space(3))) void*)dst, 16, 0, 0);
    }
  };

  stage(0, 0);
  __syncthreads();   // compiler emits vmcnt(0) drain before s_barrier

  const int lr = ch * 32 + l31;      // this lane's B row within staged tile
  const int lbase = lr * 256;
  const int lm = lr & 15;

  for (int g = 0; g < 16; ++g) {
    int cur = g & 1;
    if (g + 1 < 16) stage(g + 1, cur ^ 1);      // issue next-tile loads early

    int c0 = colblock + g * 64 + ch * 32;        // wave tile's global col base
    int tcol = tgt[c0 + l31];                    // prefetch class of this lane's col

    f32x16 acc;
#pragma unroll
    for (int r = 0; r < 16; ++r) acc[r] = 0.f;
    const char* lb = lds[cur];
#pragma unroll
    for (int kk = 0; kk < 8; ++kk) {
      v8s bf = *reinterpret_cast<const v8s*>(lb + lbase + (((2 * kk + h) ^ lm) << 4));
      acc = __builtin_amdgcn_mfma_f32_32x32x16_bf16(afrag[kk], bf, acc, 0, 0, 0);
    }

    if (c0 != rwb) {  // wave-uniform: no diagonal element in this tile
#pragma unroll
      for (int r = 0; r < 16; ++r) {
        float e = exp2f(acc[r]);     // scale pre-folded into operands
        tot_acc[r] += e;
        pos_acc[r] += (tcol == trow[r]) ? e : 0.f;
      }
    } else {          // diagonal tile: zero out row==col element
#pragma unroll
      for (int r = 0; r < 16; ++r) {
        float e = exp2f(acc[r]);
        if (l31 == ((r & 3) + 8 * (r >> 2) + 4 * h)) e = 0.f;
        tot_acc[r] += e;
        pos_acc[r] += (tcol == trow[r]) ? e : 0.f;
      }
    }
    __syncthreads();  // drains this iteration's stage (vmcnt0) + guards buffer reuse
  }

  // reduce over 32 cols (lanes of each half) then across wave pairs via LDS
#pragma unroll
  for (int r = 0; r < 16; ++r) {
    float p = pos_acc[r], q = tot_acc[r];
#pragma unroll
    for (int m = 1; m <= 16; m <<= 1) {
      p += __shfl_xor(p, m);
      q += __shfl_xor(q, m);
    }
    if (l31 == 0) {
      int rl = (r & 3) + 8 * (r >> 2) + 4 * h;
      red_pos[wave][rl] = p;
      red_tot[wave][rl] = q;
    }
  }
  __syncthreads();
  if (tid < 64) {
    int gg = tid >> 5, rl = tid & 31;
    int row = rowstrip * 64 + gg * 32 + rl;
    float p = red_pos[2 * gg][rl] + red_pos[2 * gg + 1][rl];
    float q = red_tot[2 * gg][rl] + red_tot[2 * gg + 1][rl];
    // partials in the free half of row's slot: pos[cq] @ +256B, tot[cq] @ +288B
    float* slot = reinterpret_cast<float*>(reinterpret_cast<char*>(buf) + (size_t)row * SLOT + 256);
    slot[cq] = p;
    slot[8 + cq] = q;
  }
}

// ---------------- Kernel 3: per-row loss + class aggregation -> scalar ----------------
__global__ __launch_bounds__(1024) void k_tail(const float* __restrict__ buf,
                                               const int* __restrict__ tgt,
                                               float* __restrict__ out) {
  __shared__ float cs[NCLS], cc[NCLS];
  int tid = threadIdx.x;
  if (tid < NCLS) { cs[tid] = 0.f; cc[tid] = 0.f; }
  __syncthreads();
#pragma unroll
  for (int j = 0; j < 8; ++j) {
    int row = j * 1024 + tid;
    const float4* s4 = reinterpret_cast<const float4*>(
        reinterpret_cast<const char*>(buf) + (size_t)row * SLOT + 256);
    float4 a = s4[0], b = s4[1], c4 = s4[2], d4 = s4[3];
    float pos = a.x + a.y + a.z + a.w + b.x + b.y + b.z + b.w;
    float tot = c4.x + c4.y + c4.z + c4.w + d4.x + d4.y + d4.z + d4.w;
    float loss = logf(tot) - logf(pos);   // -log(pos/tot)
    int c = tgt[row];
    atomicAdd(&cs[c], loss);
    atomicAdd(&cc[c], 1.0f);
  }
  __syncthreads();
  if (tid < 64) {
    int c = tid;  // lanes >= 16 contribute zeros
    float s = 0.f, n = 0.f;
    if (c < NCLS) { s = cs[c]; n = cc[c]; }
    float safe = fmaxf(n, 1.0f);
    float mean = s / safe;
    float inv = (n > 0.5f) ? 1.0f / safe : 0.f;     // counts>0
    float valid = (n > 1.5f) ? 1.f : 0.f;           // counts>1
    float w = (n > 1.5f) ? mean * inv : 0.f;        // select avoids 0*inf -> NaN
    float sinv = inv, sw = w, sv = valid;
#pragma unroll
    for (int m = 1; m <= 32; m <<= 1) {
      sinv += __shfl_xor(sinv, m);
      sw += __shfl_xor(sw, m);
      sv += __shfl_xor(sv, m);
    }
    if (c == 0) out[0] = sw / sinv / sv;  // sum(mean*inv)/sum(inv)/n_valid
  }
}

extern "C" void kernel_launch(void* const* d_in, const int* in_sizes, int n_in,
                              void* d_out, int out_size, void* d_ws, size_t ws_size,
                              hipStream_t stream) {
  float* buf = (float*)d_in[0];        // in-place scratch; harness restores
  const int* tgt = (const int*)d_in[1];
  const float* temp = (const float*)d_in[2];
  float* out = (float*)d_out;
  (void)d_ws; (void)ws_size;           // no workspace use

  k_norm<<<N / 4, 256, 0, stream>>>(buf, temp);
  k_sim<<<1024, 256, 0, stream>>>(buf, tgt);
  k_tail<<<1, 1024, 0, stream>>>(buf, tgt, out);
}

// Round 7
// 112.617 us; speedup vs baseline: 3.0055x; 1.1663x over previous
//
#include <hip/hip_runtime.h>

#define N 8192
#define D 128
#define NCLS 16
#define SLOT 512           // bytes per row-slot in the in-place buffer
#define RSTRIDE 256        // u16 stride between consecutive xn rows

typedef unsigned short u16;
typedef __attribute__((ext_vector_type(8))) short v8s;     // 8 bf16 = 4 VGPR
typedef __attribute__((ext_vector_type(16))) float f32x16; // MFMA 32x32 accumulator

// round-to-nearest-even f32 -> bf16
static __device__ inline u16 f2bf(float f) {
  unsigned int u = __builtin_bit_cast(unsigned int, f);
  unsigned int r = u + 0x7fffu + ((u >> 16) & 1u);
  return (u16)(r >> 16);
}

// ---------------- Kernel 1: in-place row-normalize + bf16, scale folded ----------------
// Writes xn * sqrt(log2e/t): MFMA product directly yields sim*log2e/t (exp2 == exp(sim/t)).
__global__ __launch_bounds__(256) void k_norm(float* __restrict__ buf,
                                              const float* __restrict__ temp) {
  int wave = threadIdx.x >> 6;
  int lane = threadIdx.x & 63;
  int row = blockIdx.x * 4 + wave;
  const float* p = buf + (size_t)row * D + lane * 2;
  float x = p[0], y = p[1];
  float ss = x * x + y * y;
#pragma unroll
  for (int m = 32; m >= 1; m >>= 1) ss += __shfl_xor(ss, m);
  float t = fminf(fmaxf(temp[0], 0.1f), 1.0f);       // ref clamp
  float sc = sqrtf(1.4426950408889634f / t);          // sqrt(log2e / t)
  float inv = sc / fmaxf(sqrtf(ss), 1e-8f);           // ref: max(norm, EPS)
  unsigned int u0 = (unsigned int)f2bf(x * inv);
  unsigned int u1 = (unsigned int)f2bf(y * inv);
  reinterpret_cast<unsigned int*>(buf)[(size_t)row * 128 + lane] = u0 | (u1 << 16);
}

// ---------------- Kernel 2: fused sim GEMM + exp2 + masked row sums ----------------
// grid 2048 = 64 rowstrips (128 rows) x 32 col-blocks (256 cols).
// 4 waves (256 thr): wave w owns rows rwb = rowstrip*128 + w*32 (exclusively).
// Per 32-col group (8 groups): stage 32 B-rows x 256B into LDS (2x8KB double buffer,
// XOR-swizzled both sides), ALL 4 waves consume the same staged tile; each wave one
// 32x32 MFMA tile + exp2/masked-sum epilogue. In-wave row-sum only (no wave crosstalk).
__global__ __launch_bounds__(256) void k_sim(float* __restrict__ buf,
                                             const int* __restrict__ tgt) {
  __shared__ __align__(16) char lds[2][32 * 256];   // 2 x 8 KB B-tiles

  const int tid = threadIdx.x;
  const int wave = tid >> 6;
  const int lane = tid & 63;
  const int l31 = lane & 31;
  const int h = lane >> 5;
  const int lm = l31 & 15;

  const u16* xnb = reinterpret_cast<const u16*>(buf);

  const int rowstrip = blockIdx.x >> 5;   // 0..63
  const int cq = blockIdx.x & 31;         // 0..31
  const int rwb = rowstrip * 128 + wave * 32;  // this wave's 32 rows
  const int colblock = cq * 256;

  // A fragments: row = rwb + (lane&31), k = kk*16 + 8*h + j  (held whole kernel)
  v8s afrag[8];
  {
    const u16* ap = xnb + (size_t)(rwb + l31) * RSTRIDE + h * 8;
#pragma unroll
    for (int kk = 0; kk < 8; ++kk)
      afrag[kk] = *reinterpret_cast<const v8s*>(ap + kk * 16);
  }

  // class id for each of this lane's 16 accumulator rows
  int trow[16];
#pragma unroll
  for (int r = 0; r < 16; ++r)
    trow[r] = tgt[rwb + ((r & 3) + 8 * (r >> 2) + 4 * h)];

  float tot_acc[16], pos_acc[16];
#pragma unroll
  for (int r = 0; r < 16; ++r) { tot_acc[r] = 0.f; pos_acc[r] = 0.f; }

  // stage 32 rows x 256B of group g into lds[bsel]; 2 x 16B per thread.
  // linear LDS chunk L = i*256+tid -> (row=L>>4, sl=L&15); global slot = sl ^ (row&15).
  auto stage = [&](int g, int bsel) {
    int rowbase = colblock + g * 32;
#pragma unroll
    for (int i = 0; i < 2; ++i) {
      int L = i * 256 + tid;
      int row = L >> 4;
      int s = (L & 15) ^ (row & 15);
      const char* src = reinterpret_cast<const char*>(buf) +
                        (size_t)(rowbase + row) * SLOT + s * 16;
      char* dst = &lds[bsel][(i * 256 + wave * 64) * 16];  // wave-uniform base
      __builtin_amdgcn_global_load_lds(
          (const __attribute__((address_space(1))) void*)src,
          (__attribute__((address_space(3))) void*)dst, 16, 0, 0);
    }
  };

  stage(0, 0);
  __syncthreads();   // vmcnt(0) drain before s_barrier (compiler-emitted)

  const int lbase = l31 * 256;   // this lane's B row (col c0 + l31) within staged tile

  for (int g = 0; g < 8; ++g) {
    int cur = g & 1;
    if (g + 1 < 8) stage(g + 1, cur ^ 1);        // issue next-tile loads early

    int c0 = colblock + g * 32;                   // tile's global col base (all waves)
    int tcol = tgt[c0 + l31];

    f32x16 acc;
#pragma unroll
    for (int r = 0; r < 16; ++r) acc[r] = 0.f;
    const char* lb = lds[cur];
#pragma unroll
    for (int kk = 0; kk < 8; ++kk) {
      v8s bf = *reinterpret_cast<const v8s*>(lb + lbase + (((2 * kk + h) ^ lm) << 4));
      acc = __builtin_amdgcn_mfma_f32_32x32x16_bf16(afrag[kk], bf, acc, 0, 0, 0);
    }

    if (c0 != rwb) {  // wave-uniform: no diagonal element in this tile
#pragma unroll
      for (int r = 0; r < 16; ++r) {
        float e = exp2f(acc[r]);     // scale pre-folded into operands
        tot_acc[r] += e;
        pos_acc[r] += (tcol == trow[r]) ? e : 0.f;
      }
    } else {          // diagonal tile: zero out row==col element
#pragma unroll
      for (int r = 0; r < 16; ++r) {
        float e = exp2f(acc[r]);
        if (l31 == ((r & 3) + 8 * (r >> 2) + 4 * h)) e = 0.f;
        tot_acc[r] += e;
        pos_acc[r] += (tcol == trow[r]) ? e : 0.f;
      }
    }
    __syncthreads();  // drains this iteration's stage + guards buffer reuse
  }

  // in-wave row-sum over the 32 cols, then direct scattered store of partials.
  // partial layout in row's slot free half: pos[cq] @ +256+4cq, tot[cq] @ +384+4cq.
#pragma unroll
  for (int r = 0; r < 16; ++r) {
    float p = pos_acc[r], q = tot_acc[r];
#pragma unroll
    for (int m = 1; m <= 16; m <<= 1) {
      p += __shfl_xor(p, m);
      q += __shfl_xor(q, m);
    }
    if (l31 == 0) {   // lanes 0 and 32: rows crow(r,0), crow(r,1)
      int row = rwb + ((r & 3) + 8 * (r >> 2) + 4 * h);
      float* slot = reinterpret_cast<float*>(
          reinterpret_cast<char*>(buf) + (size_t)row * SLOT + 256);
      slot[cq] = p;
      slot[32 + cq] = q;
    }
  }
}

// ---------------- Kernel 3: per-row loss + per-block class partials (64 blocks) ----------
// Block b handles rows [b*128, b*128+128). Class partials written into the DEAD xn
// bytes [0,128) of slot b: sums @ floats[0..15], counts @ floats[16..31].
__global__ __launch_bounds__(128) void k_tail_a(float* __restrict__ buf,
                                                const int* __restrict__ tgt) {
  __shared__ float cs[NCLS], cc[NCLS];
  int tid = threadIdx.x;
  if (tid < NCLS) { cs[tid] = 0.f; cc[tid] = 0.f; }
  __syncthreads();
  int row = blockIdx.x * 128 + tid;
  const float4* s4 = reinterpret_cast<const float4*>(
      reinterpret_cast<const char*>(buf) + (size_t)row * SLOT + 256);
  float pos = 0.f, tot = 0.f;
#pragma unroll
  for (int i = 0; i < 8; ++i) {
    float4 a = s4[i], b = s4[8 + i];
    pos += a.x + a.y + a.z + a.w;
    tot += b.x + b.y + b.z + b.w;
  }
  float loss = logf(tot) - logf(pos);   // -log(pos/tot)
  int c = tgt[row];
  atomicAdd(&cs[c], loss);              // 128 adds to 16 addrs: negligible
  atomicAdd(&cc[c], 1.0f);
  __syncthreads();
  if (tid < 2 * NCLS) {
    float* dst = reinterpret_cast<float*>(
        reinterpret_cast<char*>(buf) + (size_t)blockIdx.x * SLOT);
    dst[tid] = (tid < NCLS) ? cs[tid] : cc[tid - NCLS];
  }
}

// ---------------- Kernel 4: final class aggregation -> scalar ----------------
__global__ __launch_bounds__(1024) void k_final(const float* __restrict__ buf,
                                                float* __restrict__ out) {
  __shared__ float cs[NCLS], cc[NCLS];
  int tid = threadIdx.x;
  if (tid < NCLS) { cs[tid] = 0.f; cc[tid] = 0.f; }
  __syncthreads();
  {  // 1024 threads = 64 blocks x 16 classes
    int b = tid >> 4, c = tid & 15;
    const float* src = reinterpret_cast<const float*>(
        reinterpret_cast<const char*>(buf) + (size_t)b * SLOT);
    atomicAdd(&cs[c], src[c]);
    atomicAdd(&cc[c], src[NCLS + c]);
  }
  __syncthreads();
  if (tid < 64) {
    int c = tid;  // lanes >= 16 contribute zeros
    float s = 0.f, n = 0.f;
    if (c < NCLS) { s = cs[c]; n = cc[c]; }
    float safe = fmaxf(n, 1.0f);
    float mean = s / safe;
    float inv = (n > 0.5f) ? 1.0f / safe : 0.f;     // counts>0
    float valid = (n > 1.5f) ? 1.f : 0.f;           // counts>1
    float w = (n > 1.5f) ? mean * inv : 0.f;        // select avoids 0*inf -> NaN
    float sinv = inv, sw = w, sv = valid;
#pragma unroll
    for (int m = 1; m <= 32; m <<= 1) {
      sinv += __shfl_xor(sinv, m);
      sw += __shfl_xor(sw, m);
      sv += __shfl_xor(sv, m);
    }
    if (c == 0) out[0] = sw / sinv / sv;  // sum(mean*inv)/sum(inv)/n_valid
  }
}

extern "C" void kernel_launch(void* const* d_in, const int* in_sizes, int n_in,
                              void* d_out, int out_size, void* d_ws, size_t ws_size,
                              hipStream_t stream) {
  float* buf = (float*)d_in[0];        // in-place scratch; harness restores
  const int* tgt = (const int*)d_in[1];
  const float* temp = (const float*)d_in[2];
  float* out = (float*)d_out;
  (void)d_ws; (void)ws_size;           // no workspace use

  k_norm<<<N / 4, 256, 0, stream>>>(buf, temp);
  k_sim<<<2048, 256, 0, stream>>>(buf, tgt);
  k_tail_a<<<64, 128, 0, stream>>>(buf, tgt);
  k_final<<<1, 1024, 0, stream>>>(buf, out);
}